// Round 4
// baseline (1076.444 us; speedup 1.0000x reference)
//
#include <hip/hip_runtime.h>
#include <hip/hip_bf16.h>
#include <math.h>

typedef float f32x4 __attribute__((ext_vector_type(4)));
typedef __bf16 bf16x8 __attribute__((ext_vector_type(8)));

#define NTOK 98
#define NWIN 2048
#define NN (NTOK * NTOK)            // 9604
#define CROW 128                    // padded cmb row stride (floats)
#define SCALE 0.17677669529663689f

__device__ __forceinline__ int swz4(int row) {
  return (((row & 3) ^ ((row >> 3) & 3)) << 4);
}

// ---------------- prep: weights->bf16, combined bias+mask (row-padded to 128) ----------------
__global__ void prep_kernel(const float* __restrict__ qkv_w, const float* __restrict__ proj_w,
                            const float* __restrict__ pbt, const int* __restrict__ rpi,
                            const float* __restrict__ mask,
                            __bf16* __restrict__ qkvw_b, __bf16* __restrict__ projw_b,
                            float* __restrict__ cmb) {
  int i = blockIdx.x * 256 + threadIdx.x;
  if (i < 768 * 256) qkvw_b[i] = (__bf16)qkv_w[i];
  if (i < 256 * 256) projw_b[i] = (__bf16)proj_w[i];
  if (i < 256 * 8 * NTOK * CROW) {
    int wmh = i / (NTOK * CROW);          // wm*8 + h
    int rem = i - wmh * (NTOK * CROW);
    int row = rem >> 7, j = rem & 127;
    if (j < NTOK) {
      int wm = wmh >> 3, h = wmh & 7;
      cmb[i] = pbt[rpi[row * NTOK + j] * 8 + h] + mask[wm * NN + row * NTOK + j];
    }
  }
}

// ---------------- fused per-window kernel (80KB LDS, 2 blocks/CU) ----------------
// LDS: Xs [98][256]bf16 swz8 @0      (50176)
//      Qs [112][32]bf16 swz4 @50176  (7168)
//      Ks [128][32]bf16 swz4 @57344  (8192)
//      VT [32][128]bf16 swz8 @65536  (8192)
//      Yp [128][32]bf16 swz4 @73728  (8192)   total 81920
__launch_bounds__(512, 4)
__global__ void fused_kernel(const float* __restrict__ x, const float* __restrict__ cmb,
                             const __bf16* __restrict__ Wqkv, const __bf16* __restrict__ Wproj,
                             const float* __restrict__ pb, float* __restrict__ out) {
  __shared__ char smem[81920];
  char* XsB = smem;
  char* QsB = smem + 50176;
  char* KsB = smem + 57344;
  char* VTB = smem + 65536;
  char* YpB = smem + 73728;

  const int win = blockIdx.x;
  const int tid = threadIdx.x;
  const int lane = tid & 63, wv = tid >> 6;
  const int lr = lane & 15, lg = lane >> 4;
  const int wm2 = wv >> 1, wn2 = wv & 1;   // QKV GEMM: 4M x 2N
  const int wm = wv >> 2, wn = wv & 3;     // proj:     2M x 4N
  const f32x4 fz = {0.f, 0.f, 0.f, 0.f};

  // ---- stage x -> Xs (fp32 -> bf16, swizzled), 98 real rows only
  const float* xw = x + (size_t)win * NTOK * 256;
  for (int c = tid; c < NTOK * 32; c += 512) {
    int row = c >> 5, slot = c & 31;
    const float* p = xw + row * 256 + slot * 8;
    float4 f0 = *(const float4*)p;
    float4 f1 = *(const float4*)(p + 4);
    bf16x8 hv;
    hv[0] = (__bf16)f0.x; hv[1] = (__bf16)f0.y; hv[2] = (__bf16)f0.z; hv[3] = (__bf16)f0.w;
    hv[4] = (__bf16)f1.x; hv[5] = (__bf16)f1.y; hv[6] = (__bf16)f1.z; hv[7] = (__bf16)f1.w;
    *(bf16x8*)(XsB + row * 512 + ((slot * 16) ^ ((row & 7) << 4))) = hv;
  }
  __syncthreads();

  f32x4 oacc[4][4] = {};    // persistent proj accumulator

  for (int h = 0; h < 8; ++h) {
    // ---- QKV partial GEMM: N=96 cols {q32,k32,v32} of head h, K=256
    f32x4 acc2[2][3] = {};
    const int c0base = wn2 * 48;
#pragma unroll
    for (int kk = 0; kk < 8; ++kk) {
      bf16x8 a[2], b[3];
#pragma unroll
      for (int m = 0; m < 2; ++m) {
        int row = wm2 * 32 + m * 16 + lr;
        int rc = row < NTOK ? row : NTOK - 1;      // clamp pad rows
        a[m] = *(const bf16x8*)(XsB + rc * 512 + ((kk * 64 + lg * 16) ^ ((rc & 7) << 4)));
      }
#pragma unroll
      for (int n = 0; n < 3; ++n) {
        int c0 = c0base + n * 16;
        int sec = c0 >> 5;
        int d = (c0 & 31) + lr;
        b[n] = *(const bf16x8*)(Wqkv + (size_t)(sec * 256 + h * 32 + d) * 256 + kk * 32 + lg * 8);
      }
#pragma unroll
      for (int m = 0; m < 2; ++m)
#pragma unroll
        for (int n = 0; n < 3; ++n)
          acc2[m][n] = __builtin_amdgcn_mfma_f32_16x16x32_bf16(a[m], b[n], acc2[m][n], 0, 0, 0);
    }
    // scatter C to Qs/Ks/VT (swizzled)
#pragma unroll
    for (int m = 0; m < 2; ++m)
#pragma unroll
      for (int n = 0; n < 3; ++n) {
        int c0 = c0base + n * 16;
        int sec = c0 >> 5;
        int d = (c0 & 31) + lr;
#pragma unroll
        for (int r = 0; r < 4; ++r) {
          int row = wm2 * 32 + m * 16 + lg * 4 + r;
          __bf16 v = (__bf16)acc2[m][n][r];
          if (sec == 0)      { if (row < 112) *(__bf16*)(QsB + row * 64 + ((2 * d) ^ swz4(row))) = v; }
          else if (sec == 1) *(__bf16*)(KsB + row * 64 + ((2 * d) ^ swz4(row))) = v;
          else               *(__bf16*)(VTB + d * 256 + ((2 * row) ^ ((d & 7) << 4))) = v;
        }
      }
    __syncthreads();   // B1: Qs/Ks/VT ready

    if (wv < 7) {
      // ---- S^T = K Q^T with permuted K-row feed so P slots == PV A-frag slots
      const int i0 = wv * 16;
      const int qrow = i0 + lr;
      bf16x8 aq = *(const bf16x8*)(QsB + qrow * 64 + ((lg * 16) ^ swz4(qrow)));
      f32x4 s[7];
#pragma unroll
      for (int jt = 0; jt < 7; ++jt) {
        int brow = ((jt >> 1) << 5) + ((lr >> 2) << 3) + ((jt & 1) << 2) + (lr & 3);
        bf16x8 bk = *(const bf16x8*)(KsB + brow * 64 + ((lg * 16) ^ swz4(brow)));
        s[jt] = __builtin_amdgcn_mfma_f32_16x16x32_bf16(bk, aq, fz, 0, 0, 0);
      }
      // lane now holds P[qrow][k], k = 32*(jt>>1) + lg*8 + (jt&1)*4 + r

      // ---- softmax fully in-register (row == lane's qrow)
      const float* cr = cmb + (size_t)((win & 255) * 8 + h) * (NTOK * CROW)
                      + (qrow < NTOK ? qrow : NTOK - 1) * CROW;
      float sv[7][4];
      float mx = -INFINITY;
#pragma unroll
      for (int jt = 0; jt < 7; ++jt) {
        int kb = ((jt >> 1) << 5) + lg * 8 + ((jt & 1) << 2);
        float4 cv = *(const float4*)(cr + kb);
#pragma unroll
        for (int r = 0; r < 4; ++r) {
          float xv = (kb + r < NTOK) ? fmaf(SCALE, s[jt][r], (&cv.x)[r]) : -INFINITY;
          sv[jt][r] = xv;
          mx = fmaxf(mx, xv);
        }
      }
      mx = fmaxf(mx, __shfl_xor(mx, 16));
      mx = fmaxf(mx, __shfl_xor(mx, 32));
      float sum = 0.f;
#pragma unroll
      for (int jt = 0; jt < 7; ++jt)
#pragma unroll
        for (int r = 0; r < 4; ++r) {
          float p = __expf(sv[jt][r] - mx);
          sv[jt][r] = p;
          sum += p;
        }
      sum += __shfl_xor(sum, 16);
      sum += __shfl_xor(sum, 32);
      const float rinv = 1.f / sum;

      // ---- build PV A-frags in-register; jt==7 slots are pure padding -> 0
      bf16x8 pa[4];
#pragma unroll
      for (int ks = 0; ks < 4; ++ks)
#pragma unroll
        for (int e = 0; e < 8; ++e) {
          int jt = 2 * ks + (e >> 2);
          pa[ks][e] = (jt < 7) ? (__bf16)(sv[jt][e & 3] * rinv) : (__bf16)0.f;
        }

      // ---- PV: K padded to 128, write Yp
#pragma unroll
      for (int dt = 0; dt < 2; ++dt) {
        f32x4 o = fz;
#pragma unroll
        for (int ks = 0; ks < 4; ++ks) {
          int vrow = dt * 16 + lr;
          bf16x8 vb = *(const bf16x8*)(VTB + vrow * 256 + ((ks * 64 + lg * 16) ^ ((vrow & 7) << 4)));
          o = __builtin_amdgcn_mfma_f32_16x16x32_bf16(pa[ks], vb, o, 0, 0, 0);
        }
#pragma unroll
        for (int r = 0; r < 4; ++r) {
          int row = i0 + lg * 4 + r;
          *(__bf16*)(YpB + row * 64 + ((2 * (dt * 16 + lr)) ^ swz4(row))) = (__bf16)o[r];
        }
      }
    }
    __syncthreads();   // B2: Yp ready

    // ---- proj partial: oacc += Yp[128][32] @ Wproj[:, h*32..+32]^T
    bf16x8 pa2[4], pbv[4];
#pragma unroll
    for (int m = 0; m < 4; ++m) {
      int row = wm * 64 + m * 16 + lr;
      pa2[m] = *(const bf16x8*)(YpB + row * 64 + ((lg * 16) ^ swz4(row)));
    }
#pragma unroll
    for (int n = 0; n < 4; ++n) {
      int grow = wn * 64 + n * 16 + lr;
      pbv[n] = *(const bf16x8*)(Wproj + (size_t)grow * 256 + h * 32 + lg * 8);
    }
#pragma unroll
    for (int m = 0; m < 4; ++m)
#pragma unroll
      for (int n = 0; n < 4; ++n)
        oacc[m][n] = __builtin_amdgcn_mfma_f32_16x16x32_bf16(pa2[m], pbv[n], oacc[m][n], 0, 0, 0);
    // next head's scatter (writes Qs/Ks/VT) happens after B2; Yp(h+1) writes after B1(h+1)
  }

  // ---- epilogue: out = oacc + proj_b, rows < 98 only
  float* ow = out + (size_t)win * NTOK * 256;
#pragma unroll
  for (int m = 0; m < 4; ++m) {
    int row0 = wm * 64 + m * 16 + lg * 4;
    if (row0 >= NTOK) continue;
#pragma unroll
    for (int n = 0; n < 4; ++n) {
      int col = wn * 64 + n * 16 + lr;
      float bv = pb[col];
#pragma unroll
      for (int r = 0; r < 4; ++r) {
        int row = row0 + r;
        if (row < NTOK) ow[(size_t)row * 256 + col] = oacc[m][n][r] + bv;
      }
    }
  }
}

// ---------------- launch ----------------
extern "C" void kernel_launch(void* const* d_in, const int* in_sizes, int n_in,
                              void* d_out, int out_size, void* d_ws, size_t ws_size,
                              hipStream_t stream) {
  const float* x      = (const float*)d_in[0];
  const float* mask   = (const float*)d_in[1];
  const float* pbt    = (const float*)d_in[2];
  const float* qkv_w  = (const float*)d_in[3];
  const float* proj_w = (const float*)d_in[4];
  const float* proj_b = (const float*)d_in[5];
  const int*   rpi    = (const int*)d_in[6];
  float* out = (float*)d_out;

  char* ws = (char*)d_ws;
  __bf16* qkvw_b  = (__bf16*)(ws);                  // 393216
  __bf16* projw_b = (__bf16*)(ws + 393216);         // 131072
  float*  cmb     = (float*) (ws + 524288);         // 256*8*98*128*4 = 102,760,448

  int prep_n = 256 * 8 * NTOK * CROW;
  prep_kernel<<<(prep_n + 255) / 256, 256, 0, stream>>>(qkv_w, proj_w, pbt, rpi, mask,
                                                        qkvw_b, projw_b, cmb);
  fused_kernel<<<NWIN, 512, 0, stream>>>(x, cmb, qkvw_b, projw_b, proj_b, out);
}

// Round 5
// 1016.303 us; speedup vs baseline: 1.0592x; 1.0592x over previous
//
#include <hip/hip_runtime.h>
#include <hip/hip_bf16.h>
#include <math.h>

typedef float f32x4 __attribute__((ext_vector_type(4)));
typedef __bf16 bf16x8 __attribute__((ext_vector_type(8)));

#define NTOK 98
#define NWIN 2048
#define NN (NTOK * NTOK)            // 9604
#define CROW 128                    // padded cmb row stride (floats)
#define SCALE 0.17677669529663689f

__device__ __forceinline__ int swz4(int row) {
  return (((row & 3) ^ ((row >> 3) & 3)) << 4);
}

// ---------------- prep: weights->bf16, combined bias+mask (row-padded to 128) ----------------
__global__ void prep_kernel(const float* __restrict__ qkv_w, const float* __restrict__ proj_w,
                            const float* __restrict__ pbt, const int* __restrict__ rpi,
                            const float* __restrict__ mask,
                            __bf16* __restrict__ qkvw_b, __bf16* __restrict__ projw_b,
                            float* __restrict__ cmb) {
  int i = blockIdx.x * 256 + threadIdx.x;
  if (i < 768 * 256) qkvw_b[i] = (__bf16)qkv_w[i];
  if (i < 256 * 256) projw_b[i] = (__bf16)proj_w[i];
  if (i < 256 * 8 * NTOK * CROW) {
    int wmh = i / (NTOK * CROW);          // wm*8 + h
    int rem = i - wmh * (NTOK * CROW);
    int row = rem >> 7, j = rem & 127;
    if (j < NTOK) {
      int wm = wmh >> 3, h = wmh & 7;
      cmb[i] = pbt[rpi[row * NTOK + j] * 8 + h] + mask[wm * NN + row * NTOK + j];
    }
  }
}

// ---------------- fused per-window kernel (80896B LDS, 2 blocks/CU) ----------------
// LDS: Xs [98][256]bf16 swz8 @0      (50176)  -- dead after head loop
//      Y  [112][256]bf16 swz8 @0     (57344)  -- alive only after head loop (reuses Xs)
//      Qs [112][32]bf16 swz4 @57344  (7168)
//      Ks [128][32]bf16 swz4 @64512  (8192)
//      VT [32][128]bf16 swz8 @72704  (8192)   total 80896
__launch_bounds__(512, 4)
__global__ void fused_kernel(const float* __restrict__ x, const float* __restrict__ cmb,
                             const __bf16* __restrict__ Wqkv, const __bf16* __restrict__ Wproj,
                             const float* __restrict__ pb, float* __restrict__ out) {
  __shared__ char smem[80896];
  char* XsB = smem;
  char* YB  = smem;
  char* QsB = smem + 57344;
  char* KsB = smem + 64512;
  char* VTB = smem + 72704;

  const int win = blockIdx.x;
  const int tid = threadIdx.x;
  const int lane = tid & 63, wv = tid >> 6;
  const int lr = lane & 15, lg = lane >> 4;
  const int wm2 = wv >> 1, wn2 = wv & 1;   // QKV GEMM: 4M x 2N
  const int wm = wv >> 2, wn = wv & 3;     // proj:     2M x 4N
  const f32x4 fz = {0.f, 0.f, 0.f, 0.f};

  // ---- stage x -> Xs (fp32 -> bf16, swizzled), 98 real rows
  const float* xw = x + (size_t)win * NTOK * 256;
  for (int c = tid; c < NTOK * 32; c += 512) {
    int row = c >> 5, slot = c & 31;
    const float* p = xw + row * 256 + slot * 8;
    float4 f0 = *(const float4*)p;
    float4 f1 = *(const float4*)(p + 4);
    bf16x8 hv;
    hv[0] = (__bf16)f0.x; hv[1] = (__bf16)f0.y; hv[2] = (__bf16)f0.z; hv[3] = (__bf16)f0.w;
    hv[4] = (__bf16)f1.x; hv[5] = (__bf16)f1.y; hv[6] = (__bf16)f1.z; hv[7] = (__bf16)f1.w;
    *(bf16x8*)(XsB + row * 512 + ((slot * 16) ^ ((row & 7) << 4))) = hv;
  }
  __syncthreads();

  bf16x8 yreg[8];                 // per-lane Y: 8 heads x (4 rows x 2 cols)
  const int i0 = wv * 16;         // i-tile of this wave (wv<7)

  for (int h = 0; h < 8; ++h) {
    // ---- QKV partial GEMM: N=96 cols {q32,k32,v32} of head h, K=256
    f32x4 acc2[2][3] = {};
    const int c0base = wn2 * 48;
#pragma unroll
    for (int kk = 0; kk < 8; ++kk) {
      bf16x8 a[2], b[3];
#pragma unroll
      for (int m = 0; m < 2; ++m) {
        int row = wm2 * 32 + m * 16 + lr;
        int rc = row < NTOK ? row : NTOK - 1;      // clamp pad rows
        a[m] = *(const bf16x8*)(XsB + rc * 512 + ((kk * 64 + lg * 16) ^ ((rc & 7) << 4)));
      }
#pragma unroll
      for (int n = 0; n < 3; ++n) {
        int c0 = c0base + n * 16;
        int sec = c0 >> 5;
        int d = (c0 & 31) + lr;
        b[n] = *(const bf16x8*)(Wqkv + (size_t)(sec * 256 + h * 32 + d) * 256 + kk * 32 + lg * 8);
      }
#pragma unroll
      for (int m = 0; m < 2; ++m)
#pragma unroll
        for (int n = 0; n < 3; ++n)
          acc2[m][n] = __builtin_amdgcn_mfma_f32_16x16x32_bf16(a[m], b[n], acc2[m][n], 0, 0, 0);
    }
    // scatter C to Qs/Ks/VT (swizzled)
#pragma unroll
    for (int m = 0; m < 2; ++m)
#pragma unroll
      for (int n = 0; n < 3; ++n) {
        int c0 = c0base + n * 16;
        int sec = c0 >> 5;
        int d = (c0 & 31) + lr;
#pragma unroll
        for (int r = 0; r < 4; ++r) {
          int row = wm2 * 32 + m * 16 + lg * 4 + r;
          __bf16 v = (__bf16)acc2[m][n][r];
          if (sec == 0)      { if (row < 112) *(__bf16*)(QsB + row * 64 + ((2 * d) ^ swz4(row))) = v; }
          else if (sec == 1) *(__bf16*)(KsB + row * 64 + ((2 * d) ^ swz4(row))) = v;
          else               *(__bf16*)(VTB + d * 256 + ((2 * row) ^ ((d & 7) << 4))) = v;
        }
      }
    __syncthreads();   // B1: Qs/Ks/VT ready

    if (wv < 7) {
      // ---- S^T = K Q^T with permuted K-row feed so P slots == PV A-frag slots
      const int qrow = i0 + lr;
      bf16x8 aq = *(const bf16x8*)(QsB + qrow * 64 + ((lg * 16) ^ swz4(qrow)));
      f32x4 s[7];
#pragma unroll
      for (int jt = 0; jt < 7; ++jt) {
        int brow = ((jt >> 1) << 5) + ((lr >> 2) << 3) + ((jt & 1) << 2) + (lr & 3);
        bf16x8 bk = *(const bf16x8*)(KsB + brow * 64 + ((lg * 16) ^ swz4(brow)));
        s[jt] = __builtin_amdgcn_mfma_f32_16x16x32_bf16(bk, aq, fz, 0, 0, 0);
      }
      // lane holds P[qrow][k], k = 32*(jt>>1) + lg*8 + 4*(jt&1) + r

      // ---- softmax fully in-register
      const float* cr = cmb + (size_t)((win & 255) * 8 + h) * (NTOK * CROW)
                      + (qrow < NTOK ? qrow : NTOK - 1) * CROW;
      float sv[7][4];
      float mx = -INFINITY;
#pragma unroll
      for (int jt = 0; jt < 7; ++jt) {
        int kb = ((jt >> 1) << 5) + lg * 8 + ((jt & 1) << 2);
        float4 cv = *(const float4*)(cr + kb);
#pragma unroll
        for (int r = 0; r < 4; ++r) {
          float xv = (kb + r < NTOK) ? fmaf(SCALE, s[jt][r], (&cv.x)[r]) : -INFINITY;
          sv[jt][r] = xv;
          mx = fmaxf(mx, xv);
        }
      }
      mx = fmaxf(mx, __shfl_xor(mx, 16));
      mx = fmaxf(mx, __shfl_xor(mx, 32));
      float sum = 0.f;
#pragma unroll
      for (int jt = 0; jt < 7; ++jt)
#pragma unroll
        for (int r = 0; r < 4; ++r) {
          float p = __expf(sv[jt][r] - mx);
          sv[jt][r] = p;
          sum += p;
        }
      sum += __shfl_xor(sum, 16);
      sum += __shfl_xor(sum, 32);
      const float rinv = 1.f / sum;

      // ---- PV A-frags; jt==7 slots are padding -> 0
      bf16x8 pa[4];
#pragma unroll
      for (int ks = 0; ks < 4; ++ks)
#pragma unroll
        for (int e = 0; e < 8; ++e) {
          int jt = 2 * ks + (e >> 2);
          pa[ks][e] = (jt < 7) ? (__bf16)(sv[jt][e & 3] * rinv) : (__bf16)0.f;
        }

      // ---- PV -> yreg[h] (no LDS round trip per head)
      bf16x8 yh;
#pragma unroll
      for (int dt = 0; dt < 2; ++dt) {
        f32x4 o = fz;
#pragma unroll
        for (int ks = 0; ks < 4; ++ks) {
          int vrow = dt * 16 + lr;
          bf16x8 vb = *(const bf16x8*)(VTB + vrow * 256 + ((ks * 64 + lg * 16) ^ ((vrow & 7) << 4)));
          o = __builtin_amdgcn_mfma_f32_16x16x32_bf16(pa[ks], vb, o, 0, 0, 0);
        }
#pragma unroll
        for (int r = 0; r < 4; ++r) yh[dt * 4 + r] = (__bf16)o[r];
      }
      yreg[h] = yh;
    }
    __syncthreads();   // B2: staging reads done before next head's scatter
  }

  // ---- dump yreg -> Y[112][256] (reuses Xs region; Xs dead now)
  if (wv < 7) {
#pragma unroll
    for (int h = 0; h < 8; ++h)
#pragma unroll
      for (int e = 0; e < 8; ++e) {
        int row = i0 + lg * 4 + (e & 3);
        int col = h * 32 + (e >> 2) * 16 + lr;
        *(__bf16*)(YB + row * 512 + ((2 * col) ^ ((row & 7) << 4))) = yreg[h][e];
      }
  }
  __syncthreads();

  // ---- proj: out = Y @ Wproj^T + b   (K = 256)
  f32x4 oacc[4][4] = {};
#pragma unroll
  for (int kk = 0; kk < 8; ++kk) {
    bf16x8 a[4], b[4];
#pragma unroll
    for (int m = 0; m < 4; ++m) {
      int row = wm * 64 + m * 16 + lr;
      int rc = row < 112 ? row : row - 16;        // rows 112-127: don't-care (never stored)
      a[m] = *(const bf16x8*)(YB + rc * 512 + ((kk * 64 + lg * 16) ^ ((rc & 7) << 4)));
    }
#pragma unroll
    for (int n = 0; n < 4; ++n) {
      int grow = wn * 64 + n * 16 + lr;
      b[n] = *(const bf16x8*)(Wproj + (size_t)grow * 256 + kk * 32 + lg * 8);
    }
#pragma unroll
    for (int m = 0; m < 4; ++m)
#pragma unroll
      for (int n = 0; n < 4; ++n)
        oacc[m][n] = __builtin_amdgcn_mfma_f32_16x16x32_bf16(a[m], b[n], oacc[m][n], 0, 0, 0);
  }

  // ---- epilogue: out = oacc + proj_b, rows < 98 only
  float* ow = out + (size_t)win * NTOK * 256;
#pragma unroll
  for (int m = 0; m < 4; ++m) {
    int row0 = wm * 64 + m * 16 + lg * 4;
    if (row0 >= NTOK) continue;
#pragma unroll
    for (int n = 0; n < 4; ++n) {
      int col = wn * 64 + n * 16 + lr;
      float bv = pb[col];
#pragma unroll
      for (int r = 0; r < 4; ++r) {
        int row = row0 + r;
        if (row < NTOK) ow[(size_t)row * 256 + col] = oacc[m][n][r] + bv;
      }
    }
  }
}

// ---------------- launch ----------------
extern "C" void kernel_launch(void* const* d_in, const int* in_sizes, int n_in,
                              void* d_out, int out_size, void* d_ws, size_t ws_size,
                              hipStream_t stream) {
  const float* x      = (const float*)d_in[0];
  const float* mask   = (const float*)d_in[1];
  const float* pbt    = (const float*)d_in[2];
  const float* qkv_w  = (const float*)d_in[3];
  const float* proj_w = (const float*)d_in[4];
  const float* proj_b = (const float*)d_in[5];
  const int*   rpi    = (const int*)d_in[6];
  float* out = (float*)d_out;

  char* ws = (char*)d_ws;
  __bf16* qkvw_b  = (__bf16*)(ws);                  // 393216
  __bf16* projw_b = (__bf16*)(ws + 393216);         // 131072
  float*  cmb     = (float*) (ws + 524288);         // 256*8*98*128*4 = 102,760,448

  int prep_n = 256 * 8 * NTOK * CROW;
  prep_kernel<<<(prep_n + 255) / 256, 256, 0, stream>>>(qkv_w, proj_w, pbt, rpi, mask,
                                                        qkvw_b, projw_b, cmb);
  fused_kernel<<<NWIN, 512, 0, stream>>>(x, cmb, qkvw_b, projw_b, proj_b, out);
}

// Round 6
// 598.277 us; speedup vs baseline: 1.7992x; 1.6987x over previous
//
#include <hip/hip_runtime.h>
#include <hip/hip_bf16.h>
#include <math.h>

typedef float f32x4 __attribute__((ext_vector_type(4)));
typedef __bf16 bf16x8 __attribute__((ext_vector_type(8)));

#define NTOK 98
#define NWIN 2048
#define NN (NTOK * NTOK)            // 9604
#define CROW 128                    // padded cmb row stride (floats)
#define SCALE 0.17677669529663689f
#define MROWS (NWIN * NTOK)         // 200704

// ---------------- async global->LDS 16B ----------------
__device__ __forceinline__ void g2l16(const void* g, void* l) {
  typedef __attribute__((address_space(1))) const unsigned int GU;
  typedef __attribute__((address_space(3))) unsigned int LU;
  __builtin_amdgcn_global_load_lds((GU*)g, (LU*)l, 16, 0, 0);
}

// ---------------- prep: weights->bf16, combined bias+mask (row-padded to 128) ----------------
__global__ void prep_kernel(const float* __restrict__ qkv_w, const float* __restrict__ proj_w,
                            const float* __restrict__ pbt, const int* __restrict__ rpi,
                            const float* __restrict__ mask,
                            __bf16* __restrict__ qkvw_b, __bf16* __restrict__ projw_b,
                            float* __restrict__ cmb) {
  int i = blockIdx.x * 256 + threadIdx.x;
  if (i < 768 * 256) qkvw_b[i] = (__bf16)qkv_w[i];
  if (i < 256 * 256) projw_b[i] = (__bf16)proj_w[i];
  if (i < 256 * 8 * NTOK * CROW) {
    int wmh = i / (NTOK * CROW);          // wm*8 + h
    int rem = i - wmh * (NTOK * CROW);
    int row = rem >> 7, j = rem & 127;
    if (j < NTOK) {
      int wm = wmh >> 3, h = wmh & 7;
      cmb[i] = pbt[rpi[row * NTOK + j] * 8 + h] + mask[wm * NN + row * NTOK + j];
    }
  }
}

// ---------------- QKV GEMM: C[M][768] = x[M][256] @ W[768][256]^T ----------------
__launch_bounds__(256)
__global__ void gemm_qkv(const float* __restrict__ A, const __bf16* __restrict__ W,
                         __bf16* __restrict__ C) {
  __shared__ __align__(16) char As[128 * 128];   // [128 rows][64 bf16] swizzled
  __shared__ __align__(16) char Bs[128 * 128];
  const int bid = blockIdx.x;
  const int m0 = (bid / 6) * 128;
  const int n0 = (bid % 6) * 128;
  const int tid = threadIdx.x;
  const int lane = tid & 63;
  const int wid = tid >> 6;
  const int wm = wid & 1, wn = wid >> 1;
  const int lr = lane & 15;
  const int lg = lane >> 4;
  f32x4 acc[4][4] = {};

  for (int k0 = 0; k0 < 256; k0 += 64) {
    // stage A: fp32 -> bf16 through regs, swizzled store
#pragma unroll
    for (int c = 0; c < 4; ++c) {
      int flat8 = tid + c * 256;
      int row = flat8 >> 3, c8 = flat8 & 7;
      const float* ap = A + (size_t)(m0 + row) * 256 + k0 + c8 * 8;
      float4 f0 = *(const float4*)ap;
      float4 f1 = *(const float4*)(ap + 4);
      bf16x8 hv;
      hv[0] = (__bf16)f0.x; hv[1] = (__bf16)f0.y; hv[2] = (__bf16)f0.z; hv[3] = (__bf16)f0.w;
      hv[4] = (__bf16)f1.x; hv[5] = (__bf16)f1.y; hv[6] = (__bf16)f1.z; hv[7] = (__bf16)f1.w;
      *(bf16x8*)(As + row * 128 + ((c8 * 16) ^ ((row & 7) << 4))) = hv;
    }
    // stage B: g2l16 with pre-swizzled global source (LDS dest linear)
#pragma unroll
    for (int it = 0; it < 4; ++it) {
      int c = wid * 4 + it;
      int row = c * 8 + (lane >> 3);
      int src_chunk = (lane & 7) ^ (row & 7);
      g2l16(W + (size_t)(n0 + row) * 256 + k0 + src_chunk * 8, (void*)(Bs + c * 1024));
    }
    __syncthreads();
#pragma unroll
    for (int kk = 0; kk < 2; ++kk) {
      bf16x8 a[4], b[4];
#pragma unroll
      for (int m = 0; m < 4; ++m) {
        int row = wm * 64 + m * 16 + lr;
        a[m] = *(const bf16x8*)(As + row * 128 + ((kk * 64 + lg * 16) ^ ((row & 7) << 4)));
      }
#pragma unroll
      for (int n = 0; n < 4; ++n) {
        int row = wn * 64 + n * 16 + lr;
        b[n] = *(const bf16x8*)(Bs + row * 128 + ((kk * 64 + lg * 16) ^ ((row & 7) << 4)));
      }
#pragma unroll
      for (int m = 0; m < 4; ++m)
#pragma unroll
        for (int n = 0; n < 4; ++n)
          acc[m][n] = __builtin_amdgcn_mfma_f32_16x16x32_bf16(a[m], b[n], acc[m][n], 0, 0, 0);
    }
    __syncthreads();
  }
#pragma unroll
  for (int m = 0; m < 4; ++m) {
    int row = m0 + wm * 64 + m * 16 + lg * 4;
#pragma unroll
    for (int n = 0; n < 4; ++n) {
      int col = n0 + wn * 64 + n * 16 + lr;
#pragma unroll
      for (int r = 0; r < 4; ++r)
        C[(size_t)(row + r) * 768 + col] = (__bf16)acc[m][n][r];
    }
  }
}

// ---------------- attention: block = (window, head), 2 waves, barrier-free core ----------------
__launch_bounds__(128)
__global__ void attn_kernel(const __bf16* __restrict__ qkv, const float* __restrict__ cmb,
                            __bf16* __restrict__ y) {
  __shared__ __align__(16) char VTB[8192];    // VT [32 d][128 j] bf16, swizzled
  // chunked XCD swizzle: hw blocks round-robin XCDs; give each XCD a contiguous window range
  int bx = blockIdx.x;
  int lb = (bx & 7) * 2048 + (bx >> 3);
  const int win = lb >> 3, h = lb & 7;
  const int tid = threadIdx.x;
  const int lane = tid & 63, wv = tid >> 6;
  const int lr = lane & 15, lg = lane >> 4;
  const f32x4 fz = {0.f, 0.f, 0.f, 0.f};

  const __bf16* qw = qkv + (size_t)win * NTOK * 768 + h * 32;
  const __bf16* kw = qw + 256;
  const __bf16* vw = qw + 512;

  // stage V transposed -> VT (clamped rows; garbage cols multiply zero P)
  for (int c = tid; c < 512; c += 128) {
    int j = c & 127; int jc = j < NTOK ? j : NTOK - 1;
    int d8 = (c >> 7) << 3;
    bf16x8 vv = *(const bf16x8*)(vw + (size_t)jc * 768 + d8);
#pragma unroll
    for (int e = 0; e < 8; ++e) {
      int d = d8 + e;
      *(__bf16*)(VTB + d * 256 + ((2 * j) ^ ((d & 7) << 4))) = vv[e];
    }
  }
  __syncthreads();

  const float* cw = cmb + (size_t)((win & 255) * 8 + h) * (NTOK * CROW);

  for (int it = wv; it < 7; it += 2) {
    const int i0 = it * 16;
    const int qrow = i0 + lr;
    const int qrowc = qrow < NTOK ? qrow : NTOK - 1;
    bf16x8 aq = *(const bf16x8*)(qw + (size_t)qrowc * 768 + lg * 8);

    // S^T = K Q^T with permuted K-row feed: lane ends holding P[i0+lr][k],
    // k = 32*(jt>>1) + lg*8 + 4*(jt&1) + r
    f32x4 s[7];
#pragma unroll
    for (int jt = 0; jt < 7; ++jt) {
      int brow = ((jt >> 1) << 5) + ((lr >> 2) << 3) + ((jt & 1) << 2) + (lr & 3);
      int browc = brow < NTOK ? brow : NTOK - 1;
      bf16x8 bk = *(const bf16x8*)(kw + (size_t)browc * 768 + lg * 8);
      s[jt] = __builtin_amdgcn_mfma_f32_16x16x32_bf16(bk, aq, fz, 0, 0, 0);
    }

    // softmax fully in-register
    const float* cr = cw + qrowc * CROW;
    float sv[7][4];
    float mx = -INFINITY;
#pragma unroll
    for (int jt = 0; jt < 7; ++jt) {
      int kb = ((jt >> 1) << 5) + lg * 8 + ((jt & 1) << 2);
      float4 cv = *(const float4*)(cr + kb);
#pragma unroll
      for (int r = 0; r < 4; ++r) {
        float xv = (kb + r < NTOK) ? fmaf(SCALE, s[jt][r], (&cv.x)[r]) : -INFINITY;
        sv[jt][r] = xv;
        mx = fmaxf(mx, xv);
      }
    }
    mx = fmaxf(mx, __shfl_xor(mx, 16));
    mx = fmaxf(mx, __shfl_xor(mx, 32));
    float sum = 0.f;
#pragma unroll
    for (int jt = 0; jt < 7; ++jt)
#pragma unroll
      for (int r = 0; r < 4; ++r) {
        float p = __expf(sv[jt][r] - mx);
        sv[jt][r] = p;
        sum += p;
      }
    sum += __shfl_xor(sum, 16);
    sum += __shfl_xor(sum, 32);
    const float rinv = 1.f / sum;

    // PV A-frags (slots match held P layout); jt==7 phantom slots -> 0
    bf16x8 pa[4];
#pragma unroll
    for (int ks = 0; ks < 4; ++ks)
#pragma unroll
      for (int e = 0; e < 8; ++e) {
        int jt = 2 * ks + (e >> 2);
        pa[ks][e] = (jt < 7) ? (__bf16)(sv[jt][e & 3] * rinv) : (__bf16)0.f;
      }

    // PV and y write
#pragma unroll
    for (int dt = 0; dt < 2; ++dt) {
      f32x4 o = fz;
#pragma unroll
      for (int ks = 0; ks < 4; ++ks) {
        int vrow = dt * 16 + lr;
        bf16x8 vb = *(const bf16x8*)(VTB + vrow * 256 + ((ks * 64 + lg * 16) ^ ((vrow & 7) << 4)));
        o = __builtin_amdgcn_mfma_f32_16x16x32_bf16(pa[ks], vb, o, 0, 0, 0);
      }
#pragma unroll
      for (int r = 0; r < 4; ++r) {
        int row = i0 + lg * 4 + r;
        if (row < NTOK)
          y[((size_t)win * NTOK + row) * 256 + h * 32 + dt * 16 + lr] = (__bf16)o[r];
      }
    }
  }
}

// ---------------- proj GEMM: out[M][256] = y[M][256] @ W[256][256]^T + b ----------------
__launch_bounds__(256)
__global__ void gemm_proj(const __bf16* __restrict__ A, const __bf16* __restrict__ W,
                          const float* __restrict__ pb, float* __restrict__ C) {
  __shared__ __align__(16) char As[128 * 128];
  __shared__ __align__(16) char Bs[128 * 128];
  const int bid = blockIdx.x;
  const int m0 = (bid / 2) * 128;
  const int n0 = (bid % 2) * 128;
  const int tid = threadIdx.x;
  const int lane = tid & 63;
  const int wid = tid >> 6;
  const int wm = wid & 1, wn = wid >> 1;
  const int lr = lane & 15;
  const int lg = lane >> 4;
  f32x4 acc[4][4] = {};

  for (int k0 = 0; k0 < 256; k0 += 64) {
#pragma unroll
    for (int it = 0; it < 4; ++it) {
      int c = wid * 4 + it;
      int row = c * 8 + (lane >> 3);
      int src_chunk = (lane & 7) ^ (row & 7);
      g2l16(A + (size_t)(m0 + row) * 256 + k0 + src_chunk * 8, (void*)(As + c * 1024));
      g2l16(W + (size_t)(n0 + row) * 256 + k0 + src_chunk * 8, (void*)(Bs + c * 1024));
    }
    __syncthreads();
#pragma unroll
    for (int kk = 0; kk < 2; ++kk) {
      bf16x8 a[4], b[4];
#pragma unroll
      for (int m = 0; m < 4; ++m) {
        int row = wm * 64 + m * 16 + lr;
        a[m] = *(const bf16x8*)(As + row * 128 + ((kk * 64 + lg * 16) ^ ((row & 7) << 4)));
      }
#pragma unroll
      for (int n = 0; n < 4; ++n) {
        int row = wn * 64 + n * 16 + lr;
        b[n] = *(const bf16x8*)(Bs + row * 128 + ((kk * 64 + lg * 16) ^ ((row & 7) << 4)));
      }
#pragma unroll
      for (int m = 0; m < 4; ++m)
#pragma unroll
        for (int n = 0; n < 4; ++n)
          acc[m][n] = __builtin_amdgcn_mfma_f32_16x16x32_bf16(a[m], b[n], acc[m][n], 0, 0, 0);
    }
    __syncthreads();
  }
#pragma unroll
  for (int m = 0; m < 4; ++m) {
    int row = m0 + wm * 64 + m * 16 + lg * 4;
#pragma unroll
    for (int n = 0; n < 4; ++n) {
      int col = n0 + wn * 64 + n * 16 + lr;
      float bv = pb[col];
#pragma unroll
      for (int r = 0; r < 4; ++r)
        C[(size_t)(row + r) * 256 + col] = acc[m][n][r] + bv;
    }
  }
}

// ---------------- launch ----------------
extern "C" void kernel_launch(void* const* d_in, const int* in_sizes, int n_in,
                              void* d_out, int out_size, void* d_ws, size_t ws_size,
                              hipStream_t stream) {
  const float* x      = (const float*)d_in[0];
  const float* mask   = (const float*)d_in[1];
  const float* pbt    = (const float*)d_in[2];
  const float* qkv_w  = (const float*)d_in[3];
  const float* proj_w = (const float*)d_in[4];
  const float* proj_b = (const float*)d_in[5];
  const int*   rpi    = (const int*)d_in[6];
  float* out = (float*)d_out;

  char* ws = (char*)d_ws;
  __bf16* qkv     = (__bf16*)(ws);                    // 200704*768*2 = 308,281,344
  __bf16* y       = (__bf16*)(ws + 308281344);        // 200704*256*2 = 102,760,448
  __bf16* qkvw_b  = (__bf16*)(ws + 411041792);        // 393,216
  __bf16* projw_b = (__bf16*)(ws + 411435008);        // 131,072
  float*  cmb     = (float*) (ws + 411566080);        // 256*8*98*128*4 = 102,760,448  (~490MB)

  int prep_n = 256 * 8 * NTOK * CROW;
  prep_kernel<<<(prep_n + 255) / 256, 256, 0, stream>>>(qkv_w, proj_w, pbt, rpi, mask,
                                                        qkvw_b, projw_b, cmb);
  gemm_qkv<<<(MROWS / 128) * 6, 256, 0, stream>>>(x, qkvw_b, qkv);
  attn_kernel<<<NWIN * 8, 128, 0, stream>>>(qkv, cmb, y);
  gemm_proj<<<(MROWS / 128) * 2, 256, 0, stream>>>(y, projw_b, proj_b, out);
}